// Round 6
// baseline (256.986 us; speedup 1.0000x reference)
//
#include <hip/hip_runtime.h>

typedef unsigned short ushort_t;
typedef unsigned int uint_t;
typedef __attribute__((ext_vector_type(8))) _Float16 f16x8;
typedef __attribute__((ext_vector_type(4))) _Float16 f16x4;
typedef __attribute__((ext_vector_type(4))) float floatx4;

#define ZDIM 32
#define KDIM 4
#define HDIM 128
#define B_TOTAL 32768
#define TB 32

// ws layout (ushort element offsets): Wd fp16 [k][n][c], Wsm fp16 [m][n][c]
#define WS_WD16 0            // 4*1024*128 = 524288
#define WS_SM16 524288       // 3*128*128 = 49152

// LDS layout (byte offsets). Round-18 change vs round-4: producer-consumer
// pipeline at TB=32 (round-3 retry WITHOUT the traffic mistake). D is
// double-buffered: GEMM waves (4-11) write D(k+1) into buf[(k+1)&1] while
// flow waves (0-3) consume D(k) from buf[k&1]. 768 threads, 1 WG/CU.
// D layout per buffer unchanged: [i][j][batch] fp16, D_BI/2=578==2 (mod 32),
// D_BJ/2=18. z fp32 transposed [i][b]; t fp16 [j][b].
#define D_BI 1156            // halves; i stride = 32*36+4
#define D_BJ 36              // halves; j stride = 32 batches + 4 pad
#define D_BUFH 36992         // halves per buffer (32*1156) = 73984 B
#define SH_D_OFF 0           // 2 bufs = 147968 B
#define AUX_PITCH 132
#define SH_AUX_OFF 0         // float [3][32][132] = 50688 B (pre-loop, aliases buf0)
#define SH_H_OFF 50688       // half [32][136] = 8704 B (pre-loop, aliases buf0; ends 59392)
#define SH_ZT_OFF 147968     // float z^T [i][36] = 4608 B (ends 152576)
#define SH_TT_OFF 152576     // half t^T [j][36] = 2304 B (ends 154880)
#define LDS_BYTES 154880     // 1 WG/CU (<= 163840)

__device__ __forceinline__ float fast_tanh(float x) {
    float e = __expf(2.0f * x);
    return 1.0f - 2.0f / (e + 1.0f);
}
__device__ __forceinline__ float f16lo(uint_t v) {
    return (float)__builtin_bit_cast(_Float16, (ushort_t)(v & 0xFFFFu));
}
__device__ __forceinline__ float f16hi(uint_t v) {
    return (float)__builtin_bit_cast(_Float16, (ushort_t)(v >> 16));
}
__device__ __forceinline__ ushort_t f2h(float x) {
    return __builtin_bit_cast(ushort_t, (_Float16)x);
}
__device__ __forceinline__ ushort4 cvt4(float4 v) {
    ushort4 o; o.x = f2h(v.x); o.y = f2h(v.y); o.z = f2h(v.z); o.w = f2h(v.w);
    return o;
}
// pack 4 floats into 2 dwords of fp16
__device__ __forceinline__ uint2 packq(const float* p) {
    uint2 r;
    r.x = (uint_t)f2h(p[0]) | ((uint_t)f2h(p[1]) << 16);
    r.y = (uint_t)f2h(p[2]) | ((uint_t)f2h(p[3]) << 16);
    return r;
}
// runtime-kk variant: kk is wave-uniform -> s_cselect + cndmask, cheap
__device__ __forceinline__ float half_at(uint2 q, int kk) {
    uint_t w = (kk & 2) ? q.y : q.x;
    return (kk & 1) ? f16hi(w) : f16lo(w);
}

// ---------------------------------------------------------------------------
// Kernel 1: convert Wd (reordered per-k-slice) and Wd1/Wd2/Wb to fp16.
// ---------------------------------------------------------------------------
__global__ __launch_bounds__(256) void convert_kernel(
    const float* __restrict__ Wd, const float* __restrict__ Wd1,
    const float* __restrict__ Wd2, const float* __restrict__ Wb,
    ushort_t* __restrict__ ws)
{
    int g = blockIdx.x * 256 + threadIdx.x;
    if (g < 131072) {
        int k = g >> 15;            // 32768 float4 per k-slice
        int rem = g & 32767;
        int n = rem >> 5;           // n = i*32+j
        int c4 = rem & 31;
        float4 v = *((const float4*)Wd + (size_t)(4 * n + k) * 32 + c4);
        ((ushort4*)(ws + WS_WD16))[g] = cvt4(v);
    } else {
        int s = g - 131072;         // [0, 12288)
        const float* src = (s < 4096) ? Wd1 : ((s < 8192) ? Wd2 : Wb);
        int r = s & 4095;
        float4 v = ((const float4*)src)[r];
        ((ushort4*)(ws + WS_SM16))[s] = cvt4(v);
    }
}

// ---------------------------------------------------------------------------
// Kernel 2: pipelined producer-consumer at TB=32. 768 threads (12 waves),
// 1 WG/CU (LDS 151 KB). Waves 4-11 = GEMM producers (128 cols each, same
// tiling/code as round-4); waves 0-3 = flow consumers (same code as
// round-4). 5 pipeline steps, one barrier each: step s = GEMM(s) || flow
// (s-1). Per-CU weight traffic identical to round-4 (4 WG-slots either
// way); the only variable is structural GEMM/flow overlap (m114).
// Loops stay rolled (round-4 spill lesson).
// ---------------------------------------------------------------------------
__global__ __launch_bounds__(768, 1) void sylv_kernel(
    const ushort_t* __restrict__ wsb,
    const float* __restrict__ hglob,
    const float* __restrict__ z0,
    const float* __restrict__ bd,
    const float* __restrict__ bd1,
    const float* __restrict__ bd2,
    const float* __restrict__ bb,
    float* __restrict__ out)
{
    extern __shared__ char smem[];
    _Float16* Dh     = (_Float16*)(smem + SH_D_OFF);
    float*    sh_aux = (float*)(smem + SH_AUX_OFF);
    _Float16* sh_h   = (_Float16*)(smem + SH_H_OFF);
    float*    sh_zt  = (float*)(smem + SH_ZT_OFF);
    _Float16* Th     = (_Float16*)(smem + SH_TT_OFF);

    const int t   = threadIdx.x;
    const int bg0 = blockIdx.x * TB;
    const int lane = t & 63, w = t >> 6;    // w = 0..11
    const int cg = w - 4;                   // GEMM column group 0..7 (w>=4)
    const int l15 = lane & 15, l4 = lane >> 4;
    // flow mapping (t < 256): fj = column/row index, fg = batch group (4 b)
    const int fj = t & 31;
    const int fg = t >> 5;          // 0..7 for t<256

    // ---- stage h (fp32 -> fp16 in LDS) and z0 transposed ----
    {
        const float4* hsrc = (const float4*)(hglob + (size_t)bg0 * HDIM);
        for (int c = t; c < 1024; c += 768) {
            int row = c >> 5, col4 = c & 31;
            float4 v = hsrc[c];
            *(ushort4*)((ushort_t*)sh_h + row * 136 + col4 * 4) = cvt4(v);
        }
        if (t < 512) {
            int zb = t >> 4;                // 0..31 (batch)
            int zi0 = (t & 15) * 2;         // i index
            float2 zv = *(const float2*)(z0 + (size_t)(bg0 + zb) * ZDIM + zi0);
            sh_zt[zi0 * 36 + zb] = zv.x;
            sh_zt[(zi0 + 1) * 36 + zb] = zv.y;
        }
    }
    __syncthreads();

    // ---- GEMM waves: A fragments (TWO 16-row tiles) + small aux GEMMs ----
    f16x8 ah[2][4];
    if (w >= 4) {
        #pragma unroll
        for (int mt = 0; mt < 2; ++mt)
            #pragma unroll
            for (int kc = 0; kc < 4; ++kc)
                ah[mt][kc] = *(const f16x8*)(sh_h + (mt * 16 + l15) * 136 + kc * 32 + l4 * 8);

        // 24 (m,ntile) jobs over 8 GEMM waves
        #pragma unroll 1
        for (int pi = 0; pi < 3; ++pi) {
            int p = cg * 3 + pi;            // [0,24)
            int m_i = p >> 3, nt = p & 7, n = nt * 16 + l15;
            const _Float16* wp = (const _Float16*)(wsb + WS_SM16) + (size_t)(m_i * 128 + n) * 128 + l4 * 8;
            floatx4 a0 = {0.f, 0.f, 0.f, 0.f}, a1 = {0.f, 0.f, 0.f, 0.f};
            #pragma unroll
            for (int kc = 0; kc < 4; ++kc) {
                f16x8 bh = *(const f16x8*)(wp + kc * 32);
                a0 = __builtin_amdgcn_mfma_f32_16x16x32_f16(ah[0][kc], bh, a0, 0, 0, 0);
                a1 = __builtin_amdgcn_mfma_f32_16x16x32_f16(ah[1][kc], bh, a1, 0, 0, 0);
            }
            const float* bv = (m_i == 0) ? bd1 : ((m_i == 1) ? bd2 : bb);
            float bias = bv[n];
            float* ap = sh_aux + m_i * (32 * AUX_PITCH) + n;
            #pragma unroll
            for (int r = 0; r < 4; ++r) {
                float v0 = a0[r] + bias, v1 = a1[r] + bias;
                if (m_i < 2) { v0 = fast_tanh(v0); v1 = fast_tanh(v1); }
                ap[(l4 * 4 + r) * AUX_PITCH] = v0;
                ap[(16 + l4 * 4 + r) * AUX_PITCH] = v1;
            }
        }
    }
    __syncthreads();

    // ---- flow threads pack aux for (fj, 4 batches) x 4 k into fp16 regs ----
    uint2 d1q[4], d2q[4], bpq[4];
    if (t < 256) {
        #pragma unroll
        for (int e = 0; e < 4; ++e) {
            const float* base = sh_aux + (4 * fg + e) * AUX_PITCH + 4 * fj;
            d1q[e] = packq(base + 0 * (32 * AUX_PITCH));
            d2q[e] = packq(base + 1 * (32 * AUX_PITCH));
            bpq[e] = packq(base + 2 * (32 * AUX_PITCH));
        }
    }
    __syncthreads();    // pack done; buf0 (aliases aux/h) may be written

    float ld4[4] = {0.f, 0.f, 0.f, 0.f};

    // ---- 5-step pipeline: step s = GEMM(s) || flow(s-1), one barrier ----
    #pragma unroll 1
    for (int s = 0; s < 5; ++s) {
        if (s < 4 && w >= 4) {
            const int kk = s;
            _Float16* buf = Dh + (kk & 1) * D_BUFH;
            const _Float16* wdk = (const _Float16*)(wsb + WS_WD16) + (size_t)kk * 131072;
            #pragma unroll 2
            for (int g = 0; g < 8; ++g) {
                int nc = cg * 128 + g * 16 + l15;
                const _Float16* w0 = wdk + (size_t)nc * 128 + l4 * 8;
                floatx4 a0 = {0.f,0.f,0.f,0.f}, a1 = {0.f,0.f,0.f,0.f};
                #pragma unroll
                for (int kc = 0; kc < 4; ++kc) {
                    f16x8 b0 = *(const f16x8*)(w0 + kc * 32);
                    a0 = __builtin_amdgcn_mfma_f32_16x16x32_f16(ah[0][kc], b0, a0, 0, 0, 0);
                    a1 = __builtin_amdgcn_mfma_f32_16x16x32_f16(ah[1][kc], b0, a1, 0, 0, 0);
                }
                int ii = nc >> 5, jj = nc & 31;
                int base = ii * D_BI + jj * D_BJ;       // halves
                float bias0 = bd[4 * nc + kk];
                f16x4 o0, o1;
                #pragma unroll
                for (int r = 0; r < 4; ++r) {
                    o0[r] = (_Float16)(a0[r] + bias0);
                    o1[r] = (_Float16)(a1[r] + bias0);
                }
                *(f16x4*)(buf + base + l4 * 4) = o0;          // batches l4*4..+3
                *(f16x4*)(buf + base + 16 + l4 * 4) = o1;     // batches 16+l4*4..+3
            }
        }
        if (s > 0 && t < 256) {
            const int kk = s - 1;
            const _Float16* buf = Dh + (kk & 1) * D_BUFH;
            const bool flip = (kk & 1) != 0;
            const int zr_j = flip ? (31 - fj) : fj;

            // ---- pre[j][b] = bp + z_per[j]*d2 + sum_{i>j} z_per[i]*D[i,j,b] ----
            float s4[4];
            {
                floatx4 zj = *(const floatx4*)(sh_zt + zr_j * 36 + 4 * fg);
                #pragma unroll
                for (int e = 0; e < 4; ++e)
                    s4[e] = half_at(bpq[e], kk) + zj[e] * half_at(d2q[e], kk);
            }
            #pragma unroll 4
            for (int i = 0; i < 32; ++i) {      // i=0 contributes 0 (gt false)
                int zr_i = flip ? (31 - i) : i;
                floatx4 zi4 = *(const floatx4*)(sh_zt + zr_i * 36 + 4 * fg); // broadcast
                f16x4 dd = *(const f16x4*)(buf + i * D_BI + fj * D_BJ + 4 * fg);
                bool gt = (i > fj);
                #pragma unroll
                for (int e = 0; e < 4; ++e)
                    s4[e] = fmaf((float)dd[e], gt ? zi4[e] : 0.0f, s4[e]);
            }
            // ---- tanh, log-det, t -> LDS (fp16) ----
            float tq4[4];
            {
                f16x4 tth;
                #pragma unroll
                for (int e = 0; e < 4; ++e) {
                    float tt = fast_tanh(s4[e]);
                    tq4[e] = tt;
                    tth[e] = (_Float16)tt;
                    float d1 = half_at(d1q[e], kk), d2 = half_at(d2q[e], kk);
                    ld4[e] += __logf(fabsf((1.f - tt * tt) * (d1 * d2) + 1.f));
                }
                *(f16x4*)(Th + fj * 36 + 4 * fg) = tth;
            }
            // t producer (lane j') and consumer (lane p) share the 32-lane
            // group: intra-wave handoff; wait + memory clobber pins ordering.
            asm volatile("s_waitcnt lgkmcnt(0)" ::: "memory");

            // ---- dz[p][b] = t[p]*d1 + sum_{j>p} t[j][b]*D[p,j,b] ----
            float dzv4[4];
            #pragma unroll
            for (int e = 0; e < 4; ++e)
                dzv4[e] = tq4[e] * half_at(d1q[e], kk);
            #pragma unroll 4
            for (int j2 = 0; j2 < 32; ++j2) {   // j2=0 contributes 0 (gt false)
                f16x4 tt4 = *(const f16x4*)(Th + j2 * 36 + 4 * fg);       // broadcast
                f16x4 dd  = *(const f16x4*)(buf + fj * D_BI + j2 * D_BJ + 4 * fg);
                bool gt = (j2 > fj);
                #pragma unroll
                for (int e = 0; e < 4; ++e)
                    dzv4[e] = fmaf((float)dd[e], gt ? (float)tt4[e] : 0.0f, dzv4[e]);
            }
            // ---- z[b][zr_j] += dz ----
            float* zp = sh_zt + zr_j * 36 + 4 * fg;
            floatx4 zc = *(floatx4*)zp;
            #pragma unroll
            for (int e = 0; e < 4; ++e) zc[e] += dzv4[e];
            *(floatx4*)zp = zc;
        }
        __syncthreads();
    }

    // ---- epilogue: write z and log_det_j ----
    if (t < 256) {
        floatx4 zf = *(const floatx4*)(sh_zt + fj * 36 + 4 * fg);
        #pragma unroll
        for (int e = 0; e < 4; ++e)
            out[(size_t)(bg0 + 4 * fg + e) * ZDIM + fj] = zf[e];
        #pragma unroll
        for (int e = 0; e < 4; ++e) {
            float v = ld4[e];
            v += __shfl_xor(v, 1, 32);
            v += __shfl_xor(v, 2, 32);
            v += __shfl_xor(v, 4, 32);
            v += __shfl_xor(v, 8, 32);
            v += __shfl_xor(v, 16, 32);
            if (fj == 0) out[(size_t)B_TOTAL * ZDIM + bg0 + 4 * fg + e] = v;
        }
    }
}

extern "C" void kernel_launch(void* const* d_in, const int* in_sizes, int n_in,
                              void* d_out, int out_size, void* d_ws, size_t ws_size,
                              hipStream_t stream) {
    const float* z0  = (const float*)d_in[0];
    const float* h   = (const float*)d_in[1];
    const float* Wd  = (const float*)d_in[2];
    const float* bd  = (const float*)d_in[3];
    const float* Wd1 = (const float*)d_in[4];
    const float* bd1 = (const float*)d_in[5];
    const float* Wd2 = (const float*)d_in[6];
    const float* bd2 = (const float*)d_in[7];
    const float* Wb  = (const float*)d_in[8];
    const float* bb  = (const float*)d_in[9];
    ushort_t* ws = (ushort_t*)d_ws;
    float* out = (float*)d_out;

    convert_kernel<<<560, 256, 0, stream>>>(Wd, Wd1, Wd2, Wb, ws);

    (void)hipFuncSetAttribute((const void*)sylv_kernel,
                              hipFuncAttributeMaxDynamicSharedMemorySize, LDS_BYTES);
    sylv_kernel<<<B_TOTAL / TB, 768, LDS_BYTES, stream>>>(ws, h, z0, bd, bd1, bd2, bb, out);
}

// Round 7
// 203.906 us; speedup vs baseline: 1.2603x; 1.2603x over previous
//
#include <hip/hip_runtime.h>

typedef unsigned short ushort_t;
typedef unsigned int uint_t;
typedef __attribute__((ext_vector_type(8))) _Float16 f16x8;
typedef __attribute__((ext_vector_type(4))) _Float16 f16x4;
typedef __attribute__((ext_vector_type(4))) float floatx4;

#define ZDIM 32
#define KDIM 4
#define HDIM 128
#define B_TOTAL 32768
#define TB 64

// ws layout (ushort element offsets): Wd fp16 [k][n][c], Wsm fp16 [m][n][c]
#define WS_WD16 0            // 4*1024*128 = 524288
#define WS_SM16 524288       // 3*128*128 = 49152

// LDS layout (byte offsets). Round-19 change vs round-4: TB 32 -> 64.
// Evidence (r1/r2/r4/r5 + r3's 2x-WGs = 2x-time): per-CU cost is ~44 us
// per WG-SLOT, nearly independent of work per WG -> halve the WG count,
// double work per WG. GEMM gains 2 more A-row-tiles (same weight reads,
// amortized over 2x batches); flow now uses ALL 512 threads (waves 4-7
// no longer idle during flow). 1 WG/CU (LDS 152.6 KB), 2 slots/CU.
// D fp16 [i][j][b64+4pad]: D_PJ=68 halves (34 words == 2 mod 32),
// D_BI=32*68+4=2180 halves (1090 words == 2 mod 32) -> pre/dz reads
// ~2-4-way conflicts. z fp32 transposed [i][b64+4]; t fp16 [j][b64+4].
#define D_PJ 68              // halves; j stride = 64 batches + 4 pad
#define D_BI 2180            // halves; i stride = 32*68+4
#define SH_D_OFF 0           // 32*2180*2 = 139520 B
#define AUX_PITCH 132
#define AUX_MS (64 * AUX_PITCH)
#define SH_AUX_OFF 0         // float [3][64][132] = 101376 B (pre-loop, aliases D)
#define SH_H_OFF 101376      // half [64][136] = 17408 B (pre-loop, aliases D; ends 118784)
#define SH_ZT_OFF 139520     // float z^T [32][68] = 8704 B (ends 148224)
#define SH_TT_OFF 148224     // half t^T [32][68] = 4352 B (ends 152576)
#define LDS_BYTES 152576     // 1 WG/CU (<= 163840)

__device__ __forceinline__ float fast_tanh(float x) {
    float e = __expf(2.0f * x);
    return 1.0f - 2.0f / (e + 1.0f);
}
__device__ __forceinline__ float f16lo(uint_t v) {
    return (float)__builtin_bit_cast(_Float16, (ushort_t)(v & 0xFFFFu));
}
__device__ __forceinline__ float f16hi(uint_t v) {
    return (float)__builtin_bit_cast(_Float16, (ushort_t)(v >> 16));
}
__device__ __forceinline__ ushort_t f2h(float x) {
    return __builtin_bit_cast(ushort_t, (_Float16)x);
}
__device__ __forceinline__ ushort4 cvt4(float4 v) {
    ushort4 o; o.x = f2h(v.x); o.y = f2h(v.y); o.z = f2h(v.z); o.w = f2h(v.w);
    return o;
}
// pack 4 floats into 2 dwords of fp16
__device__ __forceinline__ uint2 packq(const float* p) {
    uint2 r;
    r.x = (uint_t)f2h(p[0]) | ((uint_t)f2h(p[1]) << 16);
    r.y = (uint_t)f2h(p[2]) | ((uint_t)f2h(p[3]) << 16);
    return r;
}
// runtime-kk variant: kk is wave-uniform -> s_cselect + cndmask, cheap
__device__ __forceinline__ float half_at(uint2 q, int kk) {
    uint_t w = (kk & 2) ? q.y : q.x;
    return (kk & 1) ? f16hi(w) : f16lo(w);
}

// ---------------------------------------------------------------------------
// Kernel 1: convert Wd (reordered per-k-slice) and Wd1/Wd2/Wb to fp16.
// ---------------------------------------------------------------------------
__global__ __launch_bounds__(256) void convert_kernel(
    const float* __restrict__ Wd, const float* __restrict__ Wd1,
    const float* __restrict__ Wd2, const float* __restrict__ Wb,
    ushort_t* __restrict__ ws)
{
    int g = blockIdx.x * 256 + threadIdx.x;
    if (g < 131072) {
        int k = g >> 15;            // 32768 float4 per k-slice
        int rem = g & 32767;
        int n = rem >> 5;           // n = i*32+j
        int c4 = rem & 31;
        float4 v = *((const float4*)Wd + (size_t)(4 * n + k) * 32 + c4);
        ((ushort4*)(ws + WS_WD16))[g] = cvt4(v);
    } else {
        int s = g - 131072;         // [0, 12288)
        const float* src = (s < 4096) ? Wd1 : ((s < 8192) ? Wd2 : Wb);
        int r = s & 4095;
        float4 v = ((const float4*)src)[r];
        ((ushort4*)(ws + WS_SM16))[s] = cvt4(v);
    }
}

// ---------------------------------------------------------------------------
// Kernel 2: fused fp16 encoder GEMMs + K-step flow. TB=64 batches/WG,
// 512 threads (8 waves), 1 WG/CU, 512 WGs (2 slots/CU). Structure is
// byte-identical to round-4 except: 4 A-row-tiles (ah[4][4]), flow runs
// on all 512 threads (fg = t>>5 in [0,16)), single D buffer TB=64.
// Loops rolled (round-4 spill lesson). launch_bounds(512,2) -> 256-VGPR
// tier (2 waves/EU).
// ---------------------------------------------------------------------------
__global__ __launch_bounds__(512, 2) void sylv_kernel(
    const ushort_t* __restrict__ wsb,
    const float* __restrict__ hglob,
    const float* __restrict__ z0,
    const float* __restrict__ bd,
    const float* __restrict__ bd1,
    const float* __restrict__ bd2,
    const float* __restrict__ bb,
    float* __restrict__ out)
{
    extern __shared__ char smem[];
    _Float16* Dh     = (_Float16*)(smem + SH_D_OFF);
    float*    sh_aux = (float*)(smem + SH_AUX_OFF);
    _Float16* sh_h   = (_Float16*)(smem + SH_H_OFF);
    float*    sh_zt  = (float*)(smem + SH_ZT_OFF);
    _Float16* Th     = (_Float16*)(smem + SH_TT_OFF);

    const int t   = threadIdx.x;
    const int bg0 = blockIdx.x * TB;
    const int lane = t & 63, w = t >> 6;    // w = 0..7 = column group
    const int l15 = lane & 15, l4 = lane >> 4;
    // flow mapping (all 512 threads): fj = row/col index, fg = 4-batch group
    const int fj = t & 31;
    const int fg = t >> 5;          // 0..15

    // ---- stage h (fp32 -> fp16 in LDS) and z0 transposed ----
    {
        const float4* hsrc = (const float4*)(hglob + (size_t)bg0 * HDIM);
        #pragma unroll
        for (int it = 0; it < 4; ++it) {
            int c = t + it * 512;       // 2048 float4 chunks (64 rows x 32)
            int row = c >> 5, col4 = c & 31;
            float4 v = hsrc[c];
            *(ushort4*)((ushort_t*)sh_h + row * 136 + col4 * 4) = cvt4(v);
        }
        int zb = t >> 3;                // 0..63 (batch)
        int zi0 = (t & 7) * 4;          // i index
        float4 zv = *(const float4*)(z0 + (size_t)(bg0 + zb) * ZDIM + zi0);
        sh_zt[(zi0 + 0) * 68 + zb] = zv.x;
        sh_zt[(zi0 + 1) * 68 + zb] = zv.y;
        sh_zt[(zi0 + 2) * 68 + zb] = zv.z;
        sh_zt[(zi0 + 3) * 68 + zb] = zv.w;
    }
    __syncthreads();

    // ---- A fragments: FOUR 16-row tiles (rows 0..63), same for all waves ----
    f16x8 ah[4][4];
    #pragma unroll
    for (int mt = 0; mt < 4; ++mt)
        #pragma unroll
        for (int kc = 0; kc < 4; ++kc)
            ah[mt][kc] = *(const f16x8*)(sh_h + (mt * 16 + l15) * 136 + kc * 32 + l4 * 8);

    // ---- small GEMMs (fp16): d1, d2, bpre -> aux[m][batch][n] ----
    #pragma unroll 1
    for (int pi = 0; pi < 3; ++pi) {
        int p = w * 3 + pi;             // [0,24)
        int m_i = p >> 3, nt = p & 7, n = nt * 16 + l15;
        const _Float16* wp = (const _Float16*)(wsb + WS_SM16) + (size_t)(m_i * 128 + n) * 128 + l4 * 8;
        floatx4 a[4];
        #pragma unroll
        for (int mt = 0; mt < 4; ++mt) a[mt] = (floatx4){0.f, 0.f, 0.f, 0.f};
        #pragma unroll
        for (int kc = 0; kc < 4; ++kc) {
            f16x8 bh = *(const f16x8*)(wp + kc * 32);
            #pragma unroll
            for (int mt = 0; mt < 4; ++mt)
                a[mt] = __builtin_amdgcn_mfma_f32_16x16x32_f16(ah[mt][kc], bh, a[mt], 0, 0, 0);
        }
        const float* bv = (m_i == 0) ? bd1 : ((m_i == 1) ? bd2 : bb);
        float bias = bv[n];
        float* ap = sh_aux + m_i * AUX_MS + n;
        #pragma unroll
        for (int mt = 0; mt < 4; ++mt) {
            #pragma unroll
            for (int r = 0; r < 4; ++r) {
                float v0 = a[mt][r] + bias;
                if (m_i < 2) v0 = fast_tanh(v0);
                ap[(mt * 16 + l4 * 4 + r) * AUX_PITCH] = v0;
            }
        }
    }
    __syncthreads();

    // ---- all threads pack aux for (fj, 4 batches) x 4 k into fp16 regs ----
    uint2 d1q[4], d2q[4], bpq[4];
    {
        #pragma unroll
        for (int e = 0; e < 4; ++e) {
            const float* base = sh_aux + (4 * fg + e) * AUX_PITCH + 4 * fj;
            d1q[e] = packq(base + 0 * AUX_MS);
            d2q[e] = packq(base + 1 * AUX_MS);
            bpq[e] = packq(base + 2 * AUX_MS);
        }
    }
    __syncthreads();

    float ld4[4] = {0.f, 0.f, 0.f, 0.f};

    #pragma unroll 1
    for (int kk = 0; kk < KDIM; ++kk) {
        // ---- GEMM: D_k[b][n] = h@Wd_k^T + bd; write [i][j][b] as b64 ----
        const _Float16* wdk = (const _Float16*)(wsb + WS_WD16) + (size_t)kk * 131072;
        #pragma unroll 2
        for (int g = 0; g < 8; ++g) {
            int nc = w * 128 + g * 16 + l15;
            const _Float16* w0 = wdk + (size_t)nc * 128 + l4 * 8;
            floatx4 a[4];
            #pragma unroll
            for (int mt = 0; mt < 4; ++mt) a[mt] = (floatx4){0.f, 0.f, 0.f, 0.f};
            #pragma unroll
            for (int kc = 0; kc < 4; ++kc) {
                f16x8 b0 = *(const f16x8*)(w0 + kc * 32);
                #pragma unroll
                for (int mt = 0; mt < 4; ++mt)
                    a[mt] = __builtin_amdgcn_mfma_f32_16x16x32_f16(ah[mt][kc], b0, a[mt], 0, 0, 0);
            }
            int ii = nc >> 5, jj = nc & 31;
            int base = ii * D_BI + jj * D_PJ;       // halves
            float bias0 = bd[4 * nc + kk];
            #pragma unroll
            for (int mt = 0; mt < 4; ++mt) {
                f16x4 o;
                #pragma unroll
                for (int r = 0; r < 4; ++r)
                    o[r] = (_Float16)(a[mt][r] + bias0);
                // batches mt*16 + l4*4 .. +3
                *(f16x4*)(Dh + base + mt * 16 + l4 * 4) = o;
            }
        }
        __syncthreads();

        {
            const bool flip = (kk & 1) != 0;
            const int zr_j = flip ? (31 - fj) : fj;

            // ---- pre[j][b] = bp + z_per[j]*d2 + sum_{i>j} z_per[i]*D[i,j,b] ----
            float s4[4];
            {
                floatx4 zj = *(const floatx4*)(sh_zt + zr_j * 68 + 4 * fg);
                #pragma unroll
                for (int e = 0; e < 4; ++e)
                    s4[e] = half_at(bpq[e], kk) + zj[e] * half_at(d2q[e], kk);
            }
            #pragma unroll 4
            for (int i = 0; i < 32; ++i) {      // i=0 contributes 0 (gt false)
                int zr_i = flip ? (31 - i) : i;
                floatx4 zi4 = *(const floatx4*)(sh_zt + zr_i * 68 + 4 * fg);
                f16x4 dd = *(const f16x4*)(Dh + i * D_BI + fj * D_PJ + 4 * fg);
                bool gt = (i > fj);
                #pragma unroll
                for (int e = 0; e < 4; ++e)
                    s4[e] = fmaf((float)dd[e], gt ? zi4[e] : 0.0f, s4[e]);
            }
            // ---- tanh, log-det, t -> LDS (fp16) ----
            float tq4[4];
            {
                f16x4 tth;
                #pragma unroll
                for (int e = 0; e < 4; ++e) {
                    float tt = fast_tanh(s4[e]);
                    tq4[e] = tt;
                    tth[e] = (_Float16)tt;
                    float d1 = half_at(d1q[e], kk), d2 = half_at(d2q[e], kk);
                    ld4[e] += __logf(fabsf((1.f - tt * tt) * (d1 * d2) + 1.f));
                }
                *(f16x4*)(Th + fj * 68 + 4 * fg) = tth;
            }
            // t producer (lane j') and consumer (lane p) share the 32-lane
            // group at fixed fg: intra-wave handoff; wait + clobber pins order.
            asm volatile("s_waitcnt lgkmcnt(0)" ::: "memory");

            // ---- dz[p][b] = t[p]*d1 + sum_{j>p} t[j][b]*D[p,j,b] ----
            float dzv4[4];
            #pragma unroll
            for (int e = 0; e < 4; ++e)
                dzv4[e] = tq4[e] * half_at(d1q[e], kk);
            #pragma unroll 4
            for (int j2 = 0; j2 < 32; ++j2) {   // j2=0 contributes 0 (gt false)
                f16x4 tt4 = *(const f16x4*)(Th + j2 * 68 + 4 * fg);
                f16x4 dd  = *(const f16x4*)(Dh + fj * D_BI + j2 * D_PJ + 4 * fg);
                bool gt = (j2 > fj);
                #pragma unroll
                for (int e = 0; e < 4; ++e)
                    dzv4[e] = fmaf((float)dd[e], gt ? (float)tt4[e] : 0.0f, dzv4[e]);
            }
            // ---- z[zr_j][b] += dz ----
            float* zp = sh_zt + zr_j * 68 + 4 * fg;
            floatx4 zc = *(floatx4*)zp;
            #pragma unroll
            for (int e = 0; e < 4; ++e) zc[e] += dzv4[e];
            *(floatx4*)zp = zc;
        }
        __syncthreads();
    }

    // ---- epilogue: write z and log_det_j ----
    {
        floatx4 zf = *(const floatx4*)(sh_zt + fj * 68 + 4 * fg);
        #pragma unroll
        for (int e = 0; e < 4; ++e)
            out[(size_t)(bg0 + 4 * fg + e) * ZDIM + fj] = zf[e];
        #pragma unroll
        for (int e = 0; e < 4; ++e) {
            float v = ld4[e];
            v += __shfl_xor(v, 1, 32);
            v += __shfl_xor(v, 2, 32);
            v += __shfl_xor(v, 4, 32);
            v += __shfl_xor(v, 8, 32);
            v += __shfl_xor(v, 16, 32);
            if (fj == 0) out[(size_t)B_TOTAL * ZDIM + bg0 + 4 * fg + e] = v;
        }
    }
}

extern "C" void kernel_launch(void* const* d_in, const int* in_sizes, int n_in,
                              void* d_out, int out_size, void* d_ws, size_t ws_size,
                              hipStream_t stream) {
    const float* z0  = (const float*)d_in[0];
    const float* h   = (const float*)d_in[1];
    const float* Wd  = (const float*)d_in[2];
    const float* bd  = (const float*)d_in[3];
    const float* Wd1 = (const float*)d_in[4];
    const float* bd1 = (const float*)d_in[5];
    const float* Wd2 = (const float*)d_in[6];
    const float* bd2 = (const float*)d_in[7];
    const float* Wb  = (const float*)d_in[8];
    const float* bb  = (const float*)d_in[9];
    ushort_t* ws = (ushort_t*)d_ws;
    float* out = (float*)d_out;

    convert_kernel<<<560, 256, 0, stream>>>(Wd, Wd1, Wd2, Wb, ws);

    (void)hipFuncSetAttribute((const void*)sylv_kernel,
                              hipFuncAttributeMaxDynamicSharedMemorySize, LDS_BYTES);
    sylv_kernel<<<B_TOTAL / TB, 512, LDS_BYTES, stream>>>(ws, h, z0, bd, bd1, bd2, bb, out);
}